// Round 3
// baseline (438.449 us; speedup 1.0000x reference)
//
#include <hip/hip_runtime.h>

// MaxoutDynamic: per row of [B, 4096] fp32, zero the 2048 smallest values,
// scale the 2048 survivors by 4096/2048 = 2.0.
//
// One 256-thread block per row. Exact rank-2048 selection:
//   1. ballot/popcount exact counts of {v < WL} and {WL <= v < WU}
//      (window WL,WU = +/-0.16 straddles the row median for N(0,1) data;
//      zero LDS traffic for 87% of elements)
//   2. 256-bin histogram of ONLY the ~520 in-window elements
//   3. wave-0 prefix scan -> bin containing rank 2048, gather ~2 candidates,
//      all-pairs exact rank -> tau
//   4. block-uniform fallback: full-range 256-bin exact path if rank 2048
//      is outside the window (never taken for this data; correctness for any)
//   5. write v >= tau ? 2v : 0 with non-temporal stores

#define FEAT   4096
#define NDROP  2048
#define TPB    256
#define NBIN   256
#define CAP    512
#define WL     (-0.16f)
#define WU     (0.16f)
#define WSCALE (800.0f)   // NBIN / (WU - WL)

typedef float v4f __attribute__((ext_vector_type(4)));

__global__ __launch_bounds__(TPB)
void MaxoutDynamic_55181739819231_kernel(const float* __restrict__ in,
                                         float* __restrict__ out) {
    const int row = blockIdx.x;
    const int t   = threadIdx.x;
    const v4f* inrow  = (const v4f*)(in  + (size_t)row * FEAT);
    v4f*       outrow = (v4f*)      (out + (size_t)row * FEAT);

    __shared__ unsigned int hist[NBIN];
    __shared__ float        list[CAP];
    __shared__ unsigned int wbelow[4], wwin[4];
    __shared__ unsigned int s_cnt, s_bin, s_rank;
    __shared__ float        s_tau;

    // ---- load row: thread t owns float4 slots {t, t+256, t+512, t+768} ----
    float xs[16];
#pragma unroll
    for (int j = 0; j < 4; ++j) {
        v4f l = inrow[t + j * TPB];
        xs[4 * j + 0] = l.x;
        xs[4 * j + 1] = l.y;
        xs[4 * j + 2] = l.z;
        xs[4 * j + 3] = l.w;
    }

    // ---- exact wave counts via ballot (no LDS atomics) ----
    unsigned int cb = 0u, cw = 0u;
#pragma unroll
    for (int i = 0; i < 16; ++i) {
        cb += (unsigned int)__popcll(__ballot(xs[i] < WL));
        cw += (unsigned int)__popcll(__ballot(xs[i] >= WL && xs[i] < WU));
    }
    if ((t & 63) == 0) { wbelow[t >> 6] = cb; wwin[t >> 6] = cw; }

    hist[t] = 0u;
    if (t == 0) { s_cnt = 0u; s_tau = 0.0f; }
    __syncthreads();                                   // barrier 1

    const unsigned int below = wbelow[0] + wbelow[1] + wbelow[2] + wbelow[3];
    const unsigned int nwin  = wwin[0]  + wwin[1]  + wwin[2]  + wwin[3];

    if (below <= (unsigned)NDROP && (unsigned)NDROP < below + nwin) {
        // ================= fast path (block-uniform branch) =================
        // histogram only in-window elements
#pragma unroll
        for (int i = 0; i < 16; ++i) {
            if (xs[i] >= WL && xs[i] < WU) {
                int b = (int)((xs[i] - WL) * WSCALE);
                b = b < 0 ? 0 : (b > (NBIN - 1) ? (NBIN - 1) : b);
                atomicAdd(&hist[b], 1u);
            }
        }
        __syncthreads();                               // barrier 2

        if (t < 64) {
            unsigned int c0 = hist[4 * t + 0];
            unsigned int c1 = hist[4 * t + 1];
            unsigned int c2 = hist[4 * t + 2];
            unsigned int c3 = hist[4 * t + 3];
            unsigned int sum = c0 + c1 + c2 + c3;
            unsigned int incl = sum;
#pragma unroll
            for (int d = 1; d < 64; d <<= 1) {
                unsigned int y = __shfl_up(incl, d, 64);
                if (t >= d) incl += y;
            }
            unsigned int excl = incl - sum;
            unsigned int rr = (unsigned)NDROP - below;   // rank within window
            if (rr >= excl && rr < excl + sum) {
                rr -= excl;
                unsigned int d;
                if (rr < c0) { d = 0u; }
                else { rr -= c0;
                    if (rr < c1) { d = 1u; }
                    else { rr -= c1;
                        if (rr < c2) { d = 2u; }
                        else { rr -= c2; d = 3u; } } }
                s_bin  = 4u * (unsigned int)t + d;
                s_rank = rr;
            }
        }
        __syncthreads();                               // barrier 3

        const unsigned int selbin = s_bin;
#pragma unroll
        for (int i = 0; i < 16; ++i) {
            if (xs[i] >= WL && xs[i] < WU) {
                int b = (int)((xs[i] - WL) * WSCALE);
                b = b < 0 ? 0 : (b > (NBIN - 1) ? (NBIN - 1) : b);
                if ((unsigned)b == selbin) {
                    unsigned int idx = atomicAdd(&s_cnt, 1u);
                    if (idx < CAP) list[idx] = xs[i];
                }
            }
        }
        __syncthreads();                               // barrier 4

        if (t < 64) {
            int n = (int)s_cnt; if (n > CAP) n = CAP;
            const unsigned int rr = s_rank;
            for (int c = t; c < n; c += 64) {
                float vc = list[c];
                unsigned int r = 0u, m = 0u;
                for (int j = 0; j < n; ++j) {
                    float vj = list[j];
                    r += (vj < vc) ? 1u : 0u;
                    m += (vj == vc) ? 1u : 0u;
                }
                if (r <= rr && rr < r + m) s_tau = vc;
            }
        }
        __syncthreads();                               // barrier 5
    } else {
        // ============== fallback: exact full-range path (never for N(0,1)) ==
        hist[t] = 0u;
        if (t == 0) s_cnt = 0u;
        __syncthreads();
#pragma unroll
        for (int i = 0; i < 16; ++i) {
            int b = (int)((xs[i] + 4.0f) * 32.0f);     // 256 bins over [-4,4]
            b = b < 0 ? 0 : (b > (NBIN - 1) ? (NBIN - 1) : b);
            atomicAdd(&hist[b], 1u);
        }
        __syncthreads();
        if (t < 64) {
            unsigned int c0 = hist[4 * t + 0];
            unsigned int c1 = hist[4 * t + 1];
            unsigned int c2 = hist[4 * t + 2];
            unsigned int c3 = hist[4 * t + 3];
            unsigned int sum = c0 + c1 + c2 + c3;
            unsigned int incl = sum;
#pragma unroll
            for (int d = 1; d < 64; d <<= 1) {
                unsigned int y = __shfl_up(incl, d, 64);
                if (t >= d) incl += y;
            }
            unsigned int excl = incl - sum;
            unsigned int rr = (unsigned)NDROP;
            if (rr >= excl && rr < excl + sum) {
                rr -= excl;
                unsigned int d;
                if (rr < c0) { d = 0u; }
                else { rr -= c0;
                    if (rr < c1) { d = 1u; }
                    else { rr -= c1;
                        if (rr < c2) { d = 2u; }
                        else { rr -= c2; d = 3u; } } }
                s_bin  = 4u * (unsigned int)t + d;
                s_rank = rr;
            }
        }
        __syncthreads();
        const unsigned int selbin = s_bin;
#pragma unroll
        for (int i = 0; i < 16; ++i) {
            int b = (int)((xs[i] + 4.0f) * 32.0f);
            b = b < 0 ? 0 : (b > (NBIN - 1) ? (NBIN - 1) : b);
            if ((unsigned)b == selbin) {
                unsigned int idx = atomicAdd(&s_cnt, 1u);
                if (idx < CAP) list[idx] = xs[i];
            }
        }
        __syncthreads();
        if (t < 64) {
            int n = (int)s_cnt; if (n > CAP) n = CAP;
            const unsigned int rr = s_rank;
            for (int c = t; c < n; c += 64) {
                float vc = list[c];
                unsigned int r = 0u, m = 0u;
                for (int j = 0; j < n; ++j) {
                    float vj = list[j];
                    r += (vj < vc) ? 1u : 0u;
                    m += (vj == vc) ? 1u : 0u;
                }
                if (r <= rr && rr < r + m) s_tau = vc;
            }
        }
        __syncthreads();
    }

    const float tau = s_tau;

    // ---- write: keep (x2) if v >= tau, else 0 (non-temporal stores) ----
#pragma unroll
    for (int j = 0; j < 4; ++j) {
        v4f o;
        o.x = (xs[4 * j + 0] >= tau) ? 2.0f * xs[4 * j + 0] : 0.0f;
        o.y = (xs[4 * j + 1] >= tau) ? 2.0f * xs[4 * j + 1] : 0.0f;
        o.z = (xs[4 * j + 2] >= tau) ? 2.0f * xs[4 * j + 2] : 0.0f;
        o.w = (xs[4 * j + 3] >= tau) ? 2.0f * xs[4 * j + 3] : 0.0f;
        __builtin_nontemporal_store(o, &outrow[t + j * TPB]);
    }
}

extern "C" void kernel_launch(void* const* d_in, const int* in_sizes, int n_in,
                              void* d_out, int out_size, void* d_ws, size_t ws_size,
                              hipStream_t stream) {
    const float* feat = (const float*)d_in[0];
    float* out = (float*)d_out;
    const int rows = in_sizes[0] / FEAT;   // 16384
    MaxoutDynamic_55181739819231_kernel<<<rows, TPB, 0, stream>>>(feat, out);
}